// Round 9
// baseline (384.768 us; speedup 1.0000x reference)
//
#include <hip/hip_runtime.h>

constexpr int G = 64;
constexpr int C = 16;
constexpr int NBATCH = 4;
constexpr int HID = 96;
constexpr int G3 = G * G * G; // 262144 = 2^18

typedef _Float16 h2 __attribute__((ext_vector_type(2)));

#if __has_builtin(__builtin_amdgcn_fdot2)
__device__ __forceinline__ float fdot2(h2 a, h2 b, float c) {
    return __builtin_amdgcn_fdot2(a, b, c, false);
}
#else
__device__ __forceinline__ float fdot2(h2 a, h2 b, float c) {
    return c + (float)a.x * (float)b.x + (float)a.y * (float)b.y;
}
#endif

// ---------------------------------------------------------------------------
// Pass 0: pack w1 (96x64) and w2 (16x96) to f16 pairs (15.7 KB total with b1:
// fits the 16 KB per-CU scalar K$ -- R8 proved this is worth 2x).
// ---------------------------------------------------------------------------
__global__ __launch_bounds__(256)
void nca_packw(const float* __restrict__ w1, const float* __restrict__ w2,
               h2* __restrict__ w1p, h2* __restrict__ w2p)
{
    const int i = blockIdx.x * 256 + threadIdx.x;
    if (i < HID * 32) { // w1 pairs are within a row (64 even)
        h2 v; v.x = (_Float16)w1[2 * i]; v.y = (_Float16)w1[2 * i + 1];
        w1p[i] = v;
    }
    if (i < 48 * 16) {
        const int yp = i >> 4, c = i & 15;
        h2 v; v.x = (_Float16)w2[c * HID + 2 * yp]; v.y = (_Float16)w2[c * HID + 2 * yp + 1];
        w2p[i] = v;
    }
}

// ---------------------------------------------------------------------------
// Pass 1: perception + fused f16 MLP + stochastic update.
//
// R9: 2 voxels per thread (256-thread blocks, same 8^3 tile / 2048 blocks).
// R8 stood at VALUBusy 44% with 4 waves/SIMD: each MLP iteration exposes
// ~100 cyc of s_load (K$-hit) latency against a ~350 cyc body, and a single
// dependent stream per wave can't cover it. Two voxels per thread share the
// same SGPR-resident weight rows -> per-fetch work doubles, two independent
// dot-chains interleave (ILP), same total instruction traffic.
// Register diet to stay in the 128-VGPR tier: no ctrf[] (ch0-7 old centers
// re-read from global at the end -- bit-identical, L3-hit; ch8-15 read from
// the still-resident LDS tile), premask stored before the MLP, rand loaded
// at the end.
// ---------------------------------------------------------------------------
constexpr int SY = 12;           // halo row stride
constexpr int SZ = 120;          // halo plane stride
constexpr int TILE_F = 10 * SZ;  // 1200 floats per channel

__device__ __forceinline__ void halo_off(int i, int x0, int y0, int z0,
                                         int& vo, int& si)
{
    const int j = min(i, 999); // clamped dup-writes land on slot 999 (benign)
    const int lx = j % 10;
    const int t = j / 10;
    const int ly = t % 10, lz = t / 10;
    si = lz * SZ + ly * SY + lx;
    const int gx = min(max(x0 + lx - 1, 0), G - 1);
    const int gy = min(max(y0 + ly - 1, 0), G - 1);
    const int gz = min(max(z0 + lz - 1, 0), G - 1);
    vo = gz * (G * G) + gy * G + gx;
}

// 27-point sobel plane-sum stencil; mxo==nullptr folds the max away after
// inlining (only channel 3 needs it).
__device__ __forceinline__ void stencil_one(const float* __restrict__ buf, const int cb,
                                            float& f0, float& f1, float& f2, float& f3,
                                            float* mxo)
{
    float P0 = 0.f, P2 = 0.f, U0 = 0.f, U2 = 0.f, V0 = 0.f, V2 = 0.f;
    float ctr = 0.f, mx = -3.0e38f;
#pragma unroll
    for (int dz = 0; dz < 3; ++dz) {
        const float gzw = (dz == 1) ? 2.f : 1.f;
#pragma unroll
        for (int dy = 0; dy < 3; ++dy) {
            const float gyw = (dy == 1) ? 2.f : 1.f;
            const float* r = buf + cb + dz * SZ + dy * SY;
            const float a0 = r[0], a1 = r[1], a2 = r[2];
            const float rs = a0 + 2.f * a1 + a2;
            if (dz == 0) P0 += gyw * rs;
            if (dz == 2) P2 += gyw * rs;
            if (dy == 0) U0 += gzw * rs;
            if (dy == 2) U2 += gzw * rs;
            V0 += gzw * gyw * a0;
            V2 += gzw * gyw * a2;
            if (dz == 1 && dy == 1) ctr = a1;
            if (mxo) mx = fmaxf(mx, fmaxf(fmaxf(a0, a1), a2));
        }
    }
    f0 = ctr;
    f1 = (P0 - P2) * 0.0625f;
    f2 = (U0 - U2) * 0.0625f;
    f3 = (V0 - V2) * 0.0625f;
    if (mxo) *mxo = mx;
}

__global__ __launch_bounds__(256)
void nca_update(const float* __restrict__ state, const float* __restrict__ rand_u,
                const h2* __restrict__ w1p, const float* __restrict__ b1,
                const h2* __restrict__ w2p,
                float* __restrict__ out, float* __restrict__ premask)
{
    __shared__ float tile[8][TILE_F]; // 38400 B -> 4 blocks/CU by LDS

    const int tid = threadIdx.x;
    const int bid = blockIdx.x;
    const int bx = bid & 7, by = (bid >> 3) & 7, bz = (bid >> 6) & 7, n = bid >> 9;
    const int x0 = bx * 8, y0 = by * 8, z0 = bz * 8;
    const float* sb = state + (size_t)n * C * G3;

    // Halo staging offsets: 1000 elems / 256 threads = 4 slots each.
    int vo0, s0i, vo1, s1i, vo2, s2i, vo3, s3i;
    halo_off(tid,       x0, y0, z0, vo0, s0i);
    halo_off(tid + 256, x0, y0, z0, vo1, s1i);
    halo_off(tid + 512, x0, y0, z0, vo2, s2i);
    halo_off(tid + 768, x0, y0, z0, vo3, s3i);

    // Two voxels per thread: (lx,ly,lz) and (lx,ly,lz+4).
    const int lxl = (tid & 7) + 1, lyl = ((tid >> 3) & 7) + 1;
    const int lzA = (tid >> 6) + 1;            // 1..4
    const int gx = x0 + lxl - 1, gy = y0 + lyl - 1;
    const int gzA = z0 + lzA - 1, gzB = gzA + 4;
    const size_t vofsA = (size_t)gzA * (G * G) + (size_t)gy * G + gx;
    const size_t vofsB = (size_t)gzB * (G * G) + (size_t)gy * G + gx;

    const int cbA = (lzA - 1) * SZ + (lyl - 1) * SY + (lxl - 1);
    const int cbB = cbA + 4 * SZ;

    // Packed perception features: pair j <-> features (2j, 2j+1) of each
    // sobel kernel k; pp[k*8 + c/2] pairs channels (c, c+1).
    h2 ppA[32], ppB[32];
    float pfA0 = 0.f, pfA1 = 0.f, pfA2 = 0.f, pfA3 = 0.f;
    float pfB0 = 0.f, pfB1 = 0.f, pfB2 = 0.f, pfB3 = 0.f;
    float amaxA = -3.0e38f, amaxB = -3.0e38f;

#pragma unroll
    for (int g = 0; g < 2; ++g) {
        const float* sg = sb + (size_t)(g * 8) * G3;

        if (g) __syncthreads(); // previous group's stencil reads done (WAR)

        // Bulk-load 8 channels (zero-spill pattern: nothing lives across).
#pragma unroll
        for (int c = 0; c < 8; ++c) {
            tile[c][s0i] = sg[(size_t)c * G3 + vo0];
            tile[c][s1i] = sg[(size_t)c * G3 + vo1];
            tile[c][s2i] = sg[(size_t)c * G3 + vo2];
            tile[c][s3i] = sg[(size_t)c * G3 + vo3];
        }
        __syncthreads();

#pragma unroll
        for (int c = 0; c < 8; ++c) {
            const int cg = g * 8 + c;
            const float* buf = tile[c];
            float fA0, fA1, fA2, fA3, fB0, fB1, fB2, fB3;
            stencil_one(buf, cbA, fA0, fA1, fA2, fA3, (cg == 3) ? &amaxA : nullptr);
            stencil_one(buf, cbB, fB0, fB1, fB2, fB3, (cg == 3) ? &amaxB : nullptr);

            if (cg & 1) {
                const int j = cg >> 1;
                h2 v;
                v.x = (_Float16)pfA0; v.y = (_Float16)fA0; ppA[j]      = v;
                v.x = (_Float16)pfA1; v.y = (_Float16)fA1; ppA[8 + j]  = v;
                v.x = (_Float16)pfA2; v.y = (_Float16)fA2; ppA[16 + j] = v;
                v.x = (_Float16)pfA3; v.y = (_Float16)fA3; ppA[24 + j] = v;
                v.x = (_Float16)pfB0; v.y = (_Float16)fB0; ppB[j]      = v;
                v.x = (_Float16)pfB1; v.y = (_Float16)fB1; ppB[8 + j]  = v;
                v.x = (_Float16)pfB2; v.y = (_Float16)fB2; ppB[16 + j] = v;
                v.x = (_Float16)pfB3; v.y = (_Float16)fB3; ppB[24 + j] = v;
            } else {
                pfA0 = fA0; pfA1 = fA1; pfA2 = fA2; pfA3 = fA3;
                pfB0 = fB0; pfB1 = fB1; pfB2 = fB2; pfB3 = fB3;
            }
        }
    }

    // Pre-alive mask stores now (frees amax registers before the MLP).
    premask[(size_t)n * G3 + vofsA] = (amaxA > 0.1f) ? 1.f : 0.f;
    premask[(size_t)n * G3 + vofsB] = (amaxB > 0.1f) ? 1.f : 0.f;

    float dA[C], dB[C];
#pragma unroll
    for (int c = 0; c < C; ++c) { dA[c] = 0.f; dB[c] = 0.f; }

    // Fused MLP over y-pairs. Each wave-uniform weight fetch (K$-resident)
    // now feeds TWO voxels' dot chains -> half the per-instruction stall.
#pragma unroll 1
    for (int yp = 0; yp < 48; ++yp) {
        const h2* r0 = w1p + (2 * yp) * 32;
        const h2* r1 = r0 + 32;
        float aA0 = 0.f, aA1 = 0.f, aA2 = 0.f, aA3 = 0.f;
        float cA0 = 0.f, cA1 = 0.f, cA2 = 0.f, cA3 = 0.f;
        float aB0 = 0.f, aB1 = 0.f, aB2 = 0.f, aB3 = 0.f;
        float cB0 = 0.f, cB1 = 0.f, cB2 = 0.f, cB3 = 0.f;
#pragma unroll
        for (int j = 0; j < 32; j += 4) {
            const h2 w00 = r0[j], w01 = r0[j + 1], w02 = r0[j + 2], w03 = r0[j + 3];
            const h2 w10 = r1[j], w11 = r1[j + 1], w12 = r1[j + 2], w13 = r1[j + 3];
            aA0 = fdot2(w00, ppA[j],     aA0);
            aA1 = fdot2(w01, ppA[j + 1], aA1);
            aA2 = fdot2(w02, ppA[j + 2], aA2);
            aA3 = fdot2(w03, ppA[j + 3], aA3);
            cA0 = fdot2(w10, ppA[j],     cA0);
            cA1 = fdot2(w11, ppA[j + 1], cA1);
            cA2 = fdot2(w12, ppA[j + 2], cA2);
            cA3 = fdot2(w13, ppA[j + 3], cA3);
            aB0 = fdot2(w00, ppB[j],     aB0);
            aB1 = fdot2(w01, ppB[j + 1], aB1);
            aB2 = fdot2(w02, ppB[j + 2], aB2);
            aB3 = fdot2(w03, ppB[j + 3], aB3);
            cB0 = fdot2(w10, ppB[j],     cB0);
            cB1 = fdot2(w11, ppB[j + 1], cB1);
            cB2 = fdot2(w12, ppB[j + 2], cB2);
            cB3 = fdot2(w13, ppB[j + 3], cB3);
        }
        const float bva = b1[2 * yp], bvb = b1[2 * yp + 1];
        const float haA = fmaxf(bva + ((aA0 + aA1) + (aA2 + aA3)), 0.f);
        const float hbA = fmaxf(bvb + ((cA0 + cA1) + (cA2 + cA3)), 0.f);
        const float haB = fmaxf(bva + ((aB0 + aB1) + (aB2 + aB3)), 0.f);
        const float hbB = fmaxf(bvb + ((cB0 + cB1) + (cB2 + cB3)), 0.f);
        h2 hA; hA.x = (_Float16)haA; hA.y = (_Float16)hbA;
        h2 hB; hB.x = (_Float16)haB; hB.y = (_Float16)hbB;
        const h2* w2r = w2p + yp * 16;
#pragma unroll
        for (int c = 0; c < C; ++c) {
            const h2 w = w2r[c];
            dA[c] = fdot2(w, hA, dA[c]);
            dB[c] = fdot2(w, hB, dB[c]);
        }
    }

    const float ruA = rand_u[(size_t)n * G3 + vofsA];
    const float ruB = rand_u[(size_t)n * G3 + vofsB];
    const float mA = (ruA < 0.5f) ? 1.f : 0.f;
    const float mB = (ruB < 0.5f) ? 1.f : 0.f;

    float* ob = out + (size_t)n * C * G3;
    // ch 0-7: old center re-read from global (bit-identical, L3-hit).
#pragma unroll
    for (int c = 0; c < 8; ++c) {
        ob[(size_t)c * G3 + vofsA] = fmaf(dA[c], mA, sb[(size_t)c * G3 + vofsA]);
        ob[(size_t)c * G3 + vofsB] = fmaf(dB[c], mB, sb[(size_t)c * G3 + vofsB]);
    }
    // ch 8-15: old center still resident in the LDS tile (group 1).
#pragma unroll
    for (int c = 8; c < C; ++c) {
        ob[(size_t)c * G3 + vofsA] = fmaf(dA[c], mA, tile[c - 8][cbA + SZ + SY + 1]);
        ob[(size_t)c * G3 + vofsB] = fmaf(dB[c], mB, tile[c - 8][cbB + SZ + SY + 1]);
    }
}

// ---------------------------------------------------------------------------
// Pass 2a: post-alive pooling on the NEW alpha (read-only on d_out),
// combine with pre-alive mask in-place in d_ws. No cross-thread hazards.
// ---------------------------------------------------------------------------
__global__ __launch_bounds__(256)
void nca_postmask(const float* __restrict__ newstate, float* __restrict__ mask)
{
    const int idx = blockIdx.x * 256 + threadIdx.x; // over NBATCH*G3
    const int n = idx >> 18;
    const int v = idx & (G3 - 1);
    const int x = v & 63, y = (v >> 6) & 63, z = v >> 12;
    const float* ab = newstate + ((size_t)n * C + 3) * G3;
    float mx = -3.0e38f;
#pragma unroll
    for (int dz = -1; dz <= 1; ++dz) {
        const int zz = min(max(z + dz, 0), G - 1);
#pragma unroll
        for (int dy = -1; dy <= 1; ++dy) {
            const int yy = min(max(y + dy, 0), G - 1);
            const int xm = max(x - 1, 0), xp = min(x + 1, G - 1);
            const float* row = ab + (size_t)zz * (G * G) + (size_t)yy * G;
            mx = fmaxf(mx, fmaxf(fmaxf(row[xm], row[x]), row[xp]));
        }
    }
    const float post = (mx > 0.1f) ? 1.f : 0.f;
    mask[idx] *= post;
}

// ---------------------------------------------------------------------------
// Pass 2b: out *= mask (broadcast over channels), float4-vectorized.
// ---------------------------------------------------------------------------
__global__ __launch_bounds__(256)
void nca_apply(float4* __restrict__ out4, const float4* __restrict__ mask4)
{
    const int idx = blockIdx.x * 256 + threadIdx.x; // over NBATCH*C*G3/4
    const size_t base = (size_t)idx * 4;
    const int n = (int)(base >> 22);          // C*G3 = 2^22
    const int v = (int)(base & (G3 - 1));     // G3 = 2^18
    const float4 m = mask4[((size_t)n * G3 + v) >> 2];
    float4 o = out4[idx];
    o.x *= m.x; o.y *= m.y; o.z *= m.z; o.w *= m.w;
    out4[idx] = o;
}

extern "C" void kernel_launch(void* const* d_in, const int* in_sizes, int n_in,
                              void* d_out, int out_size, void* d_ws, size_t ws_size,
                              hipStream_t stream)
{
    const float* state  = (const float*)d_in[0];
    const float* rand_u = (const float*)d_in[1];
    const float* w1     = (const float*)d_in[2];
    const float* b1     = (const float*)d_in[3];
    const float* w2     = (const float*)d_in[4];
    float* out  = (float*)d_out;

    // Workspace layout: [0,12KB) w1p, [12KB,15KB) w2p, [16KB, 16KB+4MiB) mask.
    h2*    w1p  = (h2*)d_ws;
    h2*    w2p  = (h2*)((char*)d_ws + 12 * 1024);
    float* mask = (float*)((char*)d_ws + 16 * 1024);

    nca_packw   <<<12, 256, 0, stream>>>(w1, w2, w1p, w2p);
    nca_update  <<<NBATCH * 8 * 8 * 8, 256, 0, stream>>>(state, rand_u, w1p, b1, w2p, out, mask);
    nca_postmask<<<(NBATCH * G3) / 256, 256, 0, stream>>>(out, mask);
    nca_apply   <<<(NBATCH * C * G3 / 4) / 256, 256, 0, stream>>>((float4*)out, (const float4*)mask);
}

// Round 10
// 353.949 us; speedup vs baseline: 1.0871x; 1.0871x over previous
//
#include <hip/hip_runtime.h>

constexpr int G = 64;
constexpr int C = 16;
constexpr int NBATCH = 4;
constexpr int HID = 96;
constexpr int G3 = G * G * G; // 262144 = 2^18

typedef _Float16 h2 __attribute__((ext_vector_type(2)));

#if __has_builtin(__builtin_amdgcn_fdot2)
__device__ __forceinline__ float fdot2(h2 a, h2 b, float c) {
    return __builtin_amdgcn_fdot2(a, b, c, false);
}
#else
__device__ __forceinline__ float fdot2(h2 a, h2 b, float c) {
    return c + (float)a.x * (float)b.x + (float)a.y * (float)b.y;
}
#endif

// ---------------------------------------------------------------------------
// Pass 0: pack w1 (96x64) and w2 (16x96) to f16 pairs (15 KB total).
// ---------------------------------------------------------------------------
__global__ __launch_bounds__(256)
void nca_packw(const float* __restrict__ w1, const float* __restrict__ w2,
               h2* __restrict__ w1p, h2* __restrict__ w2p)
{
    const int i = blockIdx.x * 256 + threadIdx.x;
    if (i < HID * 32) { // w1 pairs are within a row (64 even)
        h2 v; v.x = (_Float16)w1[2 * i]; v.y = (_Float16)w1[2 * i + 1];
        w1p[i] = v;
    }
    if (i < 48 * 16) {
        const int yp = i >> 4, c = i & 15;
        h2 v; v.x = (_Float16)w2[c * HID + 2 * yp]; v.y = (_Float16)w2[c * HID + 2 * yp + 1];
        w2p[i] = v;
    }
}

// ---------------------------------------------------------------------------
// Pass 1: perception + fused f16 MLP + stochastic update.
//
// R10 = R8 (proven 329 us total) + weights moved to LDS, register-neutral.
// Occupancy law measured over R1-R9: waves/SIMD = {4,2,1} at VGPR
// {<=64, <=128, >128}; the <=64 tier is unreachable (working set ~80
// floats), R9 proved crossing 128 is catastrophic. So we stay at 2
// waves/SIMD and attack the per-wave stall instead: R8's MLP read weight
// rows via wave-uniform s_load; SMEM forces an lgkmcnt(0) drain before
// first use each iteration (no partial counting), exposing full scalar
// fetch latency every yp against a ~160-cycle body. LDS reads get counted
// lgkmcnt(N) pipelining from the compiler and the broadcast (same-address)
// read is bank-conflict-free. Register headroom for the ~12 transient
// weight VGPRs is bought by dropping ctrf[16] (ch0-7 old centers re-read
// from global = bit-identical L2/L3 hit; ch8-15 from the still-resident
// LDS tile) -- must stay <=128 VGPR, WRITE_SIZE must stay 69632 KB.
// ---------------------------------------------------------------------------
constexpr int SY = 12;           // halo row stride
constexpr int SZ = 120;          // halo plane stride
constexpr int TILE_F = 10 * SZ;  // 1200 floats per channel

__global__ __launch_bounds__(512)
void nca_update(const float* __restrict__ state, const float* __restrict__ rand_u,
                const h2* __restrict__ w1p, const float* __restrict__ b1,
                const h2* __restrict__ w2p,
                float* __restrict__ out, float* __restrict__ premask)
{
    __shared__ float tile[8][TILE_F]; // 38400 B
    __shared__ h2 lw1[HID * 32];      // 12288 B
    __shared__ h2 lw2[48 * 16];       //  3072 B
    __shared__ float lb1[HID];        //   384 B  -> 54144 B total

    const int tid = threadIdx.x;
    const int bid = blockIdx.x;
    const int bx = bid & 7, by = (bid >> 3) & 7, bz = (bid >> 6) & 7, n = bid >> 9;
    const int x0 = bx * 8, y0 = by * 8, z0 = bz * 8;
    const float* sb = state + (size_t)n * C * G3;

    // --- one-time weight staging into LDS (covered by the first barrier) ---
    {
        const unsigned* g1 = (const unsigned*)w1p;
        unsigned* s1 = (unsigned*)lw1;
        for (int i = tid; i < HID * 32; i += 512) s1[i] = g1[i];
        const unsigned* g2 = (const unsigned*)w2p;
        unsigned* s2 = (unsigned*)lw2;
        for (int i = tid; i < 48 * 16; i += 512) s2[i] = g2[i];
        if (tid < HID) lb1[tid] = b1[tid];
    }

    // --- halo source offsets + LDS targets (identical for every channel) ---
    const int i0 = tid;
    const int i1 = tid + 512;
    const bool wr1 = (i1 < 1000);
    int vo0, vo1, s0i, s1i;
    {
        int lx = i0 % 10, t = i0 / 10;
        int ly = t % 10, lz = t / 10;
        s0i = lz * SZ + ly * SY + lx;
        int gx = min(max(x0 + lx - 1, 0), G - 1);
        int gy = min(max(y0 + ly - 1, 0), G - 1);
        int gz = min(max(z0 + lz - 1, 0), G - 1);
        vo0 = gz * (G * G) + gy * G + gx;
    }
    {
        int j = min(i1, 999);
        int lx = j % 10, t = j / 10;
        int ly = t % 10, lz = t / 10;
        s1i = lz * SZ + ly * SY + lx;
        int gx = min(max(x0 + lx - 1, 0), G - 1);
        int gy = min(max(y0 + ly - 1, 0), G - 1);
        int gz = min(max(z0 + lz - 1, 0), G - 1);
        vo1 = gz * (G * G) + gy * G + gx;
    }

    const int lxl = (tid & 7) + 1, lyl = ((tid >> 3) & 7) + 1, lzl = (tid >> 6) + 1;
    const int gx = x0 + lxl - 1, gy = y0 + lyl - 1, gz = z0 + lzl - 1;
    const size_t vofs = (size_t)gz * (G * G) + (size_t)gy * G + gx;

    const int cbase = (lzl - 1) * SZ + (lyl - 1) * SY + (lxl - 1);

    // Packed perception features: pair j <-> features (2j, 2j+1) of each
    // sobel kernel k; pp[k*8 + c/2] pairs channels (c, c+1).
    h2 pp[32];
    float pf0 = 0.f, pf1 = 0.f, pf2 = 0.f, pf3 = 0.f; // even-channel carry
    float amax = -3.0e38f;

#pragma unroll
    for (int g = 0; g < 2; ++g) {
        const float* sg = sb + (size_t)(g * 8) * G3;

        if (g) __syncthreads(); // previous group's stencil reads done (WAR)

        // Bulk-load 8 channels (zero-spill pattern: nothing lives across).
#pragma unroll
        for (int c = 0; c < 8; ++c) {
            tile[c][s0i] = sg[(size_t)c * G3 + vo0];
            if (wr1) tile[c][s1i] = sg[(size_t)c * G3 + vo1];
        }
        __syncthreads(); // (g==0) also covers the weight staging above

#pragma unroll
        for (int c = 0; c < 8; ++c) {
            const int cg = g * 8 + c;
            const float* buf = tile[c];
            float P0 = 0.f, P2 = 0.f, U0 = 0.f, U2 = 0.f, V0 = 0.f, V2 = 0.f;
            float ctr = 0.f, mx = -3.0e38f;
#pragma unroll
            for (int dz = 0; dz < 3; ++dz) {
                const float gzw = (dz == 1) ? 2.f : 1.f;
#pragma unroll
                for (int dy = 0; dy < 3; ++dy) {
                    const float gyw = (dy == 1) ? 2.f : 1.f;
                    const float* r = buf + cbase + dz * SZ + dy * SY;
                    const float a0 = r[0], a1 = r[1], a2 = r[2];
                    const float rs = a0 + 2.f * a1 + a2;
                    if (dz == 0) P0 += gyw * rs;
                    if (dz == 2) P2 += gyw * rs;
                    if (dy == 0) U0 += gzw * rs;
                    if (dy == 2) U2 += gzw * rs;
                    V0 += gzw * gyw * a0;
                    V2 += gzw * gyw * a2;
                    if (dz == 1 && dy == 1) ctr = a1;
                    if (cg == 3) mx = fmaxf(mx, fmaxf(fmaxf(a0, a1), a2));
                }
            }
            if (cg == 3) amax = mx;

            const float f0 = ctr;
            const float f1 = (P0 - P2) * 0.0625f;
            const float f2 = (U0 - U2) * 0.0625f;
            const float f3 = (V0 - V2) * 0.0625f;

            if (cg & 1) {
                const int j = cg >> 1;
                h2 v;
                v.x = (_Float16)pf0; v.y = (_Float16)f0; pp[j]      = v;
                v.x = (_Float16)pf1; v.y = (_Float16)f1; pp[8 + j]  = v;
                v.x = (_Float16)pf2; v.y = (_Float16)f2; pp[16 + j] = v;
                v.x = (_Float16)pf3; v.y = (_Float16)f3; pp[24 + j] = v;
            } else {
                pf0 = f0; pf1 = f1; pf2 = f2; pf3 = f3;
            }
        }
    }

    // Pre-alive mask store now (frees amax before the MLP).
    premask[(size_t)n * G3 + vofs] = (amax > 0.1f) ? 1.f : 0.f;

    float delta[C];
#pragma unroll
    for (int c = 0; c < C; ++c) delta[c] = 0.f;

    // Fused MLP over y-pairs. Weight rows come from LDS as same-address
    // broadcast ds_reads (conflict-free, counted-lgkmcnt pipelined).
#pragma unroll 2
    for (int yp = 0; yp < 48; ++yp) {
        const h2* r0 = lw1 + (2 * yp) * 32;
        const h2* r1 = r0 + 32;
        float a0 = 0.f, a1 = 0.f, a2 = 0.f, a3 = 0.f;
        float c0 = 0.f, c1 = 0.f, c2 = 0.f, c3 = 0.f;
#pragma unroll
        for (int j = 0; j < 32; j += 4) {
            a0 = fdot2(r0[j],     pp[j],     a0);
            a1 = fdot2(r0[j + 1], pp[j + 1], a1);
            a2 = fdot2(r0[j + 2], pp[j + 2], a2);
            a3 = fdot2(r0[j + 3], pp[j + 3], a3);
            c0 = fdot2(r1[j],     pp[j],     c0);
            c1 = fdot2(r1[j + 1], pp[j + 1], c1);
            c2 = fdot2(r1[j + 2], pp[j + 2], c2);
            c3 = fdot2(r1[j + 3], pp[j + 3], c3);
        }
        const float ha = fmaxf(lb1[2 * yp]     + ((a0 + a1) + (a2 + a3)), 0.f);
        const float hb = fmaxf(lb1[2 * yp + 1] + ((c0 + c1) + (c2 + c3)), 0.f);
        h2 hh; hh.x = (_Float16)ha; hh.y = (_Float16)hb;
        const h2* w2r = lw2 + yp * 16;
#pragma unroll
        for (int c = 0; c < C; ++c) delta[c] = fdot2(w2r[c], hh, delta[c]);
    }

    const float ru = rand_u[(size_t)n * G3 + vofs];
    const float m = (ru < 0.5f) ? 1.f : 0.f;

    float* ob = out + (size_t)n * C * G3;
    const int ctri = cbase + SZ + SY + 1; // center of this voxel in the tile
    // ch 0-7: old center re-read from global (bit-identical, L2/L3-hit).
#pragma unroll
    for (int c = 0; c < 8; ++c) {
        ob[(size_t)c * G3 + vofs] = fmaf(delta[c], m, sb[(size_t)c * G3 + vofs]);
    }
    // ch 8-15: old center still resident in the LDS tile (group 1).
#pragma unroll
    for (int c = 8; c < C; ++c) {
        ob[(size_t)c * G3 + vofs] = fmaf(delta[c], m, tile[c - 8][ctri]);
    }
}

// ---------------------------------------------------------------------------
// Pass 2a: post-alive pooling on the NEW alpha (read-only on d_out),
// combine with pre-alive mask in-place in d_ws. No cross-thread hazards.
// ---------------------------------------------------------------------------
__global__ __launch_bounds__(256)
void nca_postmask(const float* __restrict__ newstate, float* __restrict__ mask)
{
    const int idx = blockIdx.x * 256 + threadIdx.x; // over NBATCH*G3
    const int n = idx >> 18;
    const int v = idx & (G3 - 1);
    const int x = v & 63, y = (v >> 6) & 63, z = v >> 12;
    const float* ab = newstate + ((size_t)n * C + 3) * G3;
    float mx = -3.0e38f;
#pragma unroll
    for (int dz = -1; dz <= 1; ++dz) {
        const int zz = min(max(z + dz, 0), G - 1);
#pragma unroll
        for (int dy = -1; dy <= 1; ++dy) {
            const int yy = min(max(y + dy, 0), G - 1);
            const int xm = max(x - 1, 0), xp = min(x + 1, G - 1);
            const float* row = ab + (size_t)zz * (G * G) + (size_t)yy * G;
            mx = fmaxf(mx, fmaxf(fmaxf(row[xm], row[x]), row[xp]));
        }
    }
    const float post = (mx > 0.1f) ? 1.f : 0.f;
    mask[idx] *= post;
}

// ---------------------------------------------------------------------------
// Pass 2b: out *= mask (broadcast over channels), float4-vectorized.
// ---------------------------------------------------------------------------
__global__ __launch_bounds__(256)
void nca_apply(float4* __restrict__ out4, const float4* __restrict__ mask4)
{
    const int idx = blockIdx.x * 256 + threadIdx.x; // over NBATCH*C*G3/4
    const size_t base = (size_t)idx * 4;
    const int n = (int)(base >> 22);          // C*G3 = 2^22
    const int v = (int)(base & (G3 - 1));     // G3 = 2^18
    const float4 m = mask4[((size_t)n * G3 + v) >> 2];
    float4 o = out4[idx];
    o.x *= m.x; o.y *= m.y; o.z *= m.z; o.w *= m.w;
    out4[idx] = o;
}

extern "C" void kernel_launch(void* const* d_in, const int* in_sizes, int n_in,
                              void* d_out, int out_size, void* d_ws, size_t ws_size,
                              hipStream_t stream)
{
    const float* state  = (const float*)d_in[0];
    const float* rand_u = (const float*)d_in[1];
    const float* w1     = (const float*)d_in[2];
    const float* b1     = (const float*)d_in[3];
    const float* w2     = (const float*)d_in[4];
    float* out  = (float*)d_out;

    // Workspace layout: [0,12KB) w1p, [12KB,15KB) w2p, [16KB, 16KB+4MiB) mask.
    h2*    w1p  = (h2*)d_ws;
    h2*    w2p  = (h2*)((char*)d_ws + 12 * 1024);
    float* mask = (float*)((char*)d_ws + 16 * 1024);

    nca_packw   <<<12, 256, 0, stream>>>(w1, w2, w1p, w2p);
    nca_update  <<<NBATCH * 8 * 8 * 8, 512, 0, stream>>>(state, rand_u, w1p, b1, w2p, out, mask);
    nca_postmask<<<(NBATCH * G3) / 256, 256, 0, stream>>>(out, mask);
    nca_apply   <<<(NBATCH * C * G3 / 4) / 256, 256, 0, stream>>>((float4*)out, (const float4*)mask);
}

// Round 11
// 211.335 us; speedup vs baseline: 1.8207x; 1.6748x over previous
//
#include <hip/hip_runtime.h>

constexpr int G = 64;
constexpr int C = 16;
constexpr int NBATCH = 4;
constexpr int HID = 96;
constexpr int G3 = G * G * G; // 262144 = 2^18

typedef _Float16 h2    __attribute__((ext_vector_type(2)));
typedef _Float16 f16x4 __attribute__((ext_vector_type(4)));
typedef _Float16 f16x8 __attribute__((ext_vector_type(8)));
typedef float    f32x4 __attribute__((ext_vector_type(4)));

__device__ __forceinline__ f32x4 mfma16(f16x8 a, f16x8 b, f32x4 c) {
    return __builtin_amdgcn_mfma_f32_16x16x32_f16(a, b, c, 0, 0, 0);
}

// ---------------------------------------------------------------------------
// Pass 0: pack W1 (96x64) and W2 (16x96) into MFMA A-fragment order (f16).
// A-frag for mfma_f32_16x16x32_f16: lane l holds A[row = l%16][k = (l/16)*8+j],
// j=0..7 (16B contiguous per lane). Layouts:
//   a1p[((mt*2+kt)*64 + lane)*8 + j] = w1[mt*16 + lane%16][kt*32 + (lane/16)*8 + j]
//   a2p[((kt2)*64   + lane)*8 + j] = w2[lane%16][kt2*32 + (lane/16)*8 + j]
// ---------------------------------------------------------------------------
__global__ __launch_bounds__(256)
void nca_packw(const float* __restrict__ w1, const float* __restrict__ w2,
               _Float16* __restrict__ a1p, _Float16* __restrict__ a2p)
{
    const int i = blockIdx.x * 256 + threadIdx.x; // 0..6143
    {
        const int j = i & 7, lane = (i >> 3) & 63, f = i >> 9; // f = mt*2+kt
        const int mt = f >> 1, kt = f & 1;
        const int y = mt * 16 + (lane & 15);
        const int x = kt * 32 + ((lane >> 4) << 3) + j;
        a1p[i] = (_Float16)w1[y * 64 + x];
    }
    if (i < 3 * 512) {
        const int j = i & 7, lane = (i >> 3) & 63, kt2 = i >> 9;
        const int c = lane & 15;
        const int y = kt2 * 32 + ((lane >> 4) << 3) + j;
        a2p[i] = (_Float16)w2[c * HID + y];
    }
}

// ---------------------------------------------------------------------------
// Pass 1: perception (unchanged, proven zero-spill) + MFMA MLP.
//
// R11: the MLP moves from VALU (4800 dot2/cvt instrs/thread; dot2 = 2 MACs/
// instr is the VALU ceiling; VALUBusy 44% at the hard 8-wave/CU tier) to the
// matrix pipe, which has been idle all session (MfmaUtil 0.0). Computed
// SWAPPED: H^T = W1 @ X^T (M=96,K=64,N=64 voxels/wave), delta^T = W2 @ H^T
// (M=16,K=96,N=64), so H^T lands in C-layout rows that store contiguously
// as [v][y] in LDS and read back as contiguous B2 fragments. Per wave:
// 60 MFMA + ~450 VALU replaces ~4800 VALU. All GEMM LDS is wave-private
// (no new barriers). X-panel stride 144B / H stride 80B give uniform bank
// distribution. W-fragments pre-packed by nca_packw (1 global 16B load per
// frag per lane, L2-resident).
// ---------------------------------------------------------------------------
constexpr int SY = 12;           // halo row stride
constexpr int SZ = 120;          // halo plane stride
constexpr int TILE_F = 10 * SZ;  // 1200 floats per channel
constexpr int XROW = 144;        // X-panel row stride (bytes), 64 rows = 9216 B
constexpr int HROW = 80;         // H row stride (bytes), 64 rows = 5120 B

__global__ __launch_bounds__(512)
void nca_update(const float* __restrict__ state, const float* __restrict__ rand_u,
                const _Float16* __restrict__ a1p, const float* __restrict__ b1,
                const _Float16* __restrict__ a2p,
                float* __restrict__ out, float* __restrict__ premask)
{
    __shared__ float tile[8][TILE_F];            // 38400 B
    __shared__ __align__(16) char xh[8][9216];   // 73728 B -> 112128 B total

    const int tid = threadIdx.x;
    const int bid = blockIdx.x;
    const int bx = bid & 7, by = (bid >> 3) & 7, bz = (bid >> 6) & 7, n = bid >> 9;
    const int x0 = bx * 8, y0 = by * 8, z0 = bz * 8;
    const float* sb = state + (size_t)n * C * G3;

    // --- halo source offsets + LDS targets (identical for every channel) ---
    const int i0 = tid;
    const int i1 = tid + 512;
    const bool wr1 = (i1 < 1000);
    int vo0, vo1, s0i, s1i;
    {
        int lx = i0 % 10, t = i0 / 10;
        int ly = t % 10, lz = t / 10;
        s0i = lz * SZ + ly * SY + lx;
        int gx = min(max(x0 + lx - 1, 0), G - 1);
        int gy = min(max(y0 + ly - 1, 0), G - 1);
        int gz = min(max(z0 + lz - 1, 0), G - 1);
        vo0 = gz * (G * G) + gy * G + gx;
    }
    {
        int j = min(i1, 999);
        int lx = j % 10, t = j / 10;
        int ly = t % 10, lz = t / 10;
        s1i = lz * SZ + ly * SY + lx;
        int gx = min(max(x0 + lx - 1, 0), G - 1);
        int gy = min(max(y0 + ly - 1, 0), G - 1);
        int gz = min(max(z0 + lz - 1, 0), G - 1);
        vo1 = gz * (G * G) + gy * G + gx;
    }

    const int lxl = (tid & 7) + 1, lyl = ((tid >> 3) & 7) + 1, lzl = (tid >> 6) + 1;
    const int gx = x0 + lxl - 1, gy = y0 + lyl - 1, gz = z0 + lzl - 1;
    const size_t vofs = (size_t)gz * (G * G) + (size_t)gy * G + gx;

    const int cbase = (lzl - 1) * SZ + (lyl - 1) * SY + (lxl - 1);

    // Packed perception features: h2 pp[j] = features (2j, 2j+1); feature
    // index x = k*16 + c (k: 0=ident, 1=sobel-z, 2=sobel-y, 3=sobel-x).
    h2 pp[32];
    float pf0 = 0.f, pf1 = 0.f, pf2 = 0.f, pf3 = 0.f; // even-channel carry
    float amax = -3.0e38f;

#pragma unroll
    for (int g = 0; g < 2; ++g) {
        const float* sg = sb + (size_t)(g * 8) * G3;

        if (g) __syncthreads(); // previous group's stencil reads done (WAR)

        // Bulk-load 8 channels (zero-spill pattern: nothing lives across).
#pragma unroll
        for (int c = 0; c < 8; ++c) {
            tile[c][s0i] = sg[(size_t)c * G3 + vo0];
            if (wr1) tile[c][s1i] = sg[(size_t)c * G3 + vo1];
        }
        __syncthreads();

#pragma unroll
        for (int c = 0; c < 8; ++c) {
            const int cg = g * 8 + c;
            const float* buf = tile[c];
            float P0 = 0.f, P2 = 0.f, U0 = 0.f, U2 = 0.f, V0 = 0.f, V2 = 0.f;
            float ctr = 0.f, mx = -3.0e38f;
#pragma unroll
            for (int dz = 0; dz < 3; ++dz) {
                const float gzw = (dz == 1) ? 2.f : 1.f;
#pragma unroll
                for (int dy = 0; dy < 3; ++dy) {
                    const float gyw = (dy == 1) ? 2.f : 1.f;
                    const float* r = buf + cbase + dz * SZ + dy * SY;
                    const float a0 = r[0], a1 = r[1], a2 = r[2];
                    const float rs = a0 + 2.f * a1 + a2;
                    if (dz == 0) P0 += gyw * rs;
                    if (dz == 2) P2 += gyw * rs;
                    if (dy == 0) U0 += gzw * rs;
                    if (dy == 2) U2 += gzw * rs;
                    V0 += gzw * gyw * a0;
                    V2 += gzw * gyw * a2;
                    if (dz == 1 && dy == 1) ctr = a1;
                    if (cg == 3) mx = fmaxf(mx, fmaxf(fmaxf(a0, a1), a2));
                }
            }
            if (cg == 3) amax = mx;

            const float f0 = ctr;
            const float f1 = (P0 - P2) * 0.0625f;
            const float f2 = (U0 - U2) * 0.0625f;
            const float f3 = (V0 - V2) * 0.0625f;

            if (cg & 1) {
                const int j = cg >> 1;
                h2 v;
                v.x = (_Float16)pf0; v.y = (_Float16)f0; pp[j]      = v;
                v.x = (_Float16)pf1; v.y = (_Float16)f1; pp[8 + j]  = v;
                v.x = (_Float16)pf2; v.y = (_Float16)f2; pp[16 + j] = v;
                v.x = (_Float16)pf3; v.y = (_Float16)f3; pp[24 + j] = v;
            } else {
                pf0 = f0; pf1 = f1; pf2 = f2; pf3 = f3;
            }
        }
    }

    // Pre-alive mask store (thread-own voxel; frees amax before GEMMs).
    premask[(size_t)n * G3 + vofs] = (amax > 0.1f) ? 1.f : 0.f;

    // =================== MFMA MLP (wave-private) ===================
    const int lane = tid & 63;
    const int w    = tid >> 6;       // wave = z-slice; gz_wave = z0 + w
    const int l15  = lane & 15;
    const int lg   = lane >> 4;      // lane group 0..3
    char* xw = &xh[w][0];

    // --- write X-panel: row v = lane (this thread's voxel), 64 f16 ---
#pragma unroll
    for (int q = 0; q < 8; ++q) {
        uint4 t;
        t.x = __builtin_bit_cast(unsigned, pp[4 * q]);
        t.y = __builtin_bit_cast(unsigned, pp[4 * q + 1]);
        t.z = __builtin_bit_cast(unsigned, pp[4 * q + 2]);
        t.w = __builtin_bit_cast(unsigned, pp[4 * q + 3]);
        *(uint4*)(xw + lane * XROW + q * 16) = t;
    }

    // --- load B1 fragments (X^T): B[k][v], lane: k=(lg)*8.., v=nt*16+l15 ---
    f16x8 bfr[8]; // [kt*4 + nt]
#pragma unroll
    for (int kt = 0; kt < 2; ++kt)
#pragma unroll
        for (int nt = 0; nt < 4; ++nt)
            bfr[kt * 4 + nt] = *(const f16x8*)(xw + (nt * 16 + l15) * XROW + kt * 64 + lg * 16);

    const f16x8* a1 = ((const f16x8*)a1p) + lane;
    const f16x8* a2 = ((const f16x8*)a2p) + lane;

    f32x4 acc2[4];
#pragma unroll
    for (int nt = 0; nt < 4; ++nt) acc2[nt] = (f32x4){0.f, 0.f, 0.f, 0.f};

    // --- interleaved GEMM1/GEMM2 per 32-row hidden block ---
#pragma unroll 1
    for (int kt2 = 0; kt2 < 3; ++kt2) {
#pragma unroll
        for (int mtsub = 0; mtsub < 2; ++mtsub) {
            const int mt = kt2 * 2 + mtsub;
            const f16x8 a_0 = a1[(mt * 2 + 0) * 64];
            const f16x8 a_1 = a1[(mt * 2 + 1) * 64];
            const f32x4 bias = *(const f32x4*)(b1 + mt * 16 + lg * 4);
#pragma unroll
            for (int nt = 0; nt < 4; ++nt) {
                f32x4 acc = (f32x4){0.f, 0.f, 0.f, 0.f};
                acc = mfma16(a_0, bfr[nt],     acc);
                acc = mfma16(a_1, bfr[4 + nt], acc);
                // h = relu(acc + bias), rows y = mt*16 + lg*4 + r
                f16x4 hv;
                hv[0] = (_Float16)fmaxf(acc[0] + bias[0], 0.f);
                hv[1] = (_Float16)fmaxf(acc[1] + bias[1], 0.f);
                hv[2] = (_Float16)fmaxf(acc[2] + bias[2], 0.f);
                hv[3] = (_Float16)fmaxf(acc[3] + bias[3], 0.f);
                // H stored [v][y-local] (y-local = y - kt2*32, 32 per block)
                *(f16x4*)(xw + (nt * 16 + l15) * HROW + mtsub * 32 + lg * 8) = hv;
            }
        }
        // GEMM2 partial: delta^T += W2[:, kt2-block] @ H-block
        const f16x8 a2f = a2[kt2 * 64];
#pragma unroll
        for (int nt = 0; nt < 4; ++nt) {
            const f16x8 b2 = *(const f16x8*)(xw + (nt * 16 + l15) * HROW + lg * 16);
            acc2[nt] = mfma16(a2f, b2, acc2[nt]);
        }
    }

    // --- epilogue: lane holds delta for c = lg*4+r, v = nt*16+l15 ---
    float* ob = out + (size_t)n * C * G3;
#pragma unroll
    for (int nt = 0; nt < 4; ++nt) {
        const int vv = nt * 16 + l15;
        const int vx = vv & 7, vy = vv >> 3;
        const size_t vo = (size_t)(z0 + w) * (G * G) + (size_t)(y0 + vy) * G + (x0 + vx);
        const float ru = rand_u[(size_t)n * G3 + vo];
        const float m = (ru < 0.5f) ? 1.f : 0.f;
#pragma unroll
        for (int r = 0; r < 4; ++r) {
            const int c = lg * 4 + r;
            const float s0 = sb[(size_t)c * G3 + vo];
            ob[(size_t)c * G3 + vo] = fmaf(acc2[nt][r], m, s0);
        }
    }
}

// ---------------------------------------------------------------------------
// Pass 2a: post-alive pooling on the NEW alpha (read-only on d_out),
// combine with pre-alive mask in-place in d_ws. No cross-thread hazards.
// ---------------------------------------------------------------------------
__global__ __launch_bounds__(256)
void nca_postmask(const float* __restrict__ newstate, float* __restrict__ mask)
{
    const int idx = blockIdx.x * 256 + threadIdx.x; // over NBATCH*G3
    const int n = idx >> 18;
    const int v = idx & (G3 - 1);
    const int x = v & 63, y = (v >> 6) & 63, z = v >> 12;
    const float* ab = newstate + ((size_t)n * C + 3) * G3;
    float mx = -3.0e38f;
#pragma unroll
    for (int dz = -1; dz <= 1; ++dz) {
        const int zz = min(max(z + dz, 0), G - 1);
#pragma unroll
        for (int dy = -1; dy <= 1; ++dy) {
            const int yy = min(max(y + dy, 0), G - 1);
            const int xm = max(x - 1, 0), xp = min(x + 1, G - 1);
            const float* row = ab + (size_t)zz * (G * G) + (size_t)yy * G;
            mx = fmaxf(mx, fmaxf(fmaxf(row[xm], row[x]), row[xp]));
        }
    }
    const float post = (mx > 0.1f) ? 1.f : 0.f;
    mask[idx] *= post;
}

// ---------------------------------------------------------------------------
// Pass 2b: out *= mask (broadcast over channels), float4-vectorized.
// ---------------------------------------------------------------------------
__global__ __launch_bounds__(256)
void nca_apply(float4* __restrict__ out4, const float4* __restrict__ mask4)
{
    const int idx = blockIdx.x * 256 + threadIdx.x; // over NBATCH*C*G3/4
    const size_t base = (size_t)idx * 4;
    const int n = (int)(base >> 22);          // C*G3 = 2^22
    const int v = (int)(base & (G3 - 1));     // G3 = 2^18
    const float4 m = mask4[((size_t)n * G3 + v) >> 2];
    float4 o = out4[idx];
    o.x *= m.x; o.y *= m.y; o.z *= m.z; o.w *= m.w;
    out4[idx] = o;
}

extern "C" void kernel_launch(void* const* d_in, const int* in_sizes, int n_in,
                              void* d_out, int out_size, void* d_ws, size_t ws_size,
                              hipStream_t stream)
{
    const float* state  = (const float*)d_in[0];
    const float* rand_u = (const float*)d_in[1];
    const float* w1     = (const float*)d_in[2];
    const float* b1     = (const float*)d_in[3];
    const float* w2     = (const float*)d_in[4];
    float* out  = (float*)d_out;

    // Workspace: [0,12KB) a1p, [12KB,15KB) a2p, [16KB, 16KB+4MiB) mask.
    _Float16* a1p = (_Float16*)d_ws;
    _Float16* a2p = (_Float16*)((char*)d_ws + 12 * 1024);
    float*    mask = (float*)((char*)d_ws + 16 * 1024);

    nca_packw   <<<24, 256, 0, stream>>>(w1, w2, a1p, a2p);
    nca_update  <<<NBATCH * 8 * 8 * 8, 512, 0, stream>>>(state, rand_u, a1p, b1, a2p, out, mask);
    nca_postmask<<<(NBATCH * G3) / 256, 256, 0, stream>>>(out, mask);
    nca_apply   <<<(NBATCH * C * G3 / 4) / 256, 256, 0, stream>>>((float4*)out, (const float4*)mask);
}